// Round 16
// baseline (1168.072 us; speedup 1.0000x reference)
//
#include <hip/hip_runtime.h>

typedef unsigned short u16;
typedef __attribute__((ext_vector_type(8))) short short8;
typedef __attribute__((ext_vector_type(4))) float f32x4;

#define T_TOKENS 4096
#define DMODEL   768
#define DFF      3072
#define NEXP     8
#define NVOCAB   32000

__device__ __forceinline__ u16 f2bf(float f) {
  unsigned u = __float_as_uint(f);
  u += 0x7FFFu + ((u >> 16) & 1u);
  return (u16)(u >> 16);
}
__device__ __forceinline__ float bf2f(u16 b) {
  return __uint_as_float(((unsigned)b) << 16);
}

__device__ __forceinline__ void async_load16(const void* g, void* lds) {
  __builtin_amdgcn_global_load_lds((const __attribute__((address_space(1))) void*)g,
                                   (__attribute__((address_space(3))) void*)lds, 16, 0, 0);
}

#define SBAR() __builtin_amdgcn_s_barrier()
#define VMCNT(n) asm volatile("s_waitcnt vmcnt(" #n ")")
#define SCHEDB() __builtin_amdgcn_sched_barrier(0)

__device__ __forceinline__ short8 frag(const u16* buf, int row, int kc) {
  return *(const short8*)(buf + (row * 8 + (kc ^ (row & 7))) * 8);
}

// ---------------- embed + router + top2 list build ----------------
__global__ __launch_bounds__(256) void k_embed_router(
    const int* __restrict__ x, const float* __restrict__ emb,
    const float* __restrict__ gw, const float* __restrict__ gb,
    u16* __restrict__ tbf, int* __restrict__ counts,
    int* __restrict__ tlist, float* __restrict__ wlist)
{
  __shared__ float partial[4][NEXP];
  const int t = blockIdx.x;
  const int tok = x[t];
  const float* er = emb + (size_t)tok * DMODEL;
  float p[NEXP];
#pragma unroll
  for (int e = 0; e < NEXP; ++e) p[e] = 0.f;
#pragma unroll
  for (int i = 0; i < 3; ++i) {
    const int d = threadIdx.x + i * 256;
    const float v = er[d];
    tbf[(size_t)t * DMODEL + d] = f2bf(v);
#pragma unroll
    for (int e = 0; e < NEXP; ++e) p[e] += v * gw[d * NEXP + e];
  }
#pragma unroll
  for (int e = 0; e < NEXP; ++e)
#pragma unroll
    for (int m = 32; m >= 1; m >>= 1) p[e] += __shfl_xor(p[e], m);
  const int lane = threadIdx.x & 63, wv = threadIdx.x >> 6;
  if (lane == 0)
    for (int e = 0; e < NEXP; ++e) partial[wv][e] = p[e];
  __syncthreads();
  if (threadIdx.x == 0) {
    float l[NEXP];
    for (int e = 0; e < NEXP; ++e)
      l[e] = partial[0][e] + partial[1][e] + partial[2][e] + partial[3][e] + gb[e];
    int i0 = 0;
    for (int e = 1; e < NEXP; ++e) if (l[e] > l[i0]) i0 = e;   // ties: first (jax)
    int i1 = -1;
    for (int e = 0; e < NEXP; ++e) { if (e == i0) continue; if (i1 < 0 || l[e] > l[i1]) i1 = e; }
    const float w0 = 1.f / (1.f + expf(l[i1] - l[i0]));
    int p0 = atomicAdd(&counts[0 * NEXP + i0], 1);
    tlist[(0 * NEXP + i0) * T_TOKENS + p0] = t;
    wlist[(0 * NEXP + i0) * T_TOKENS + p0] = w0;
    int p1 = atomicAdd(&counts[1 * NEXP + i1], 1);
    tlist[(1 * NEXP + i1) * T_TOKENS + p1] = t;
    wlist[(1 * NEXP + i1) * T_TOKENS + p1] = 1.f - w0;
  }
}

// ---------------- transpose + fp32->bf16 convert (64x64 tile, 16B stores) ----------------
// Store phase: thread (h=tid&7, cl=tid>>3) packs 8 consecutive-R bf16 into one
// 16B store -> 128B contiguous runs per 8 lanes (R%8==0 so aligned). LDS read
// tile[8h+j][ccl] with stride-65 pad: bank = (8h+cl+j)%32, each bank exactly
// 2x per wave = free (m136).
__global__ __launch_bounds__(256) void k_transpose_cvt(
    const float* __restrict__ src, u16* __restrict__ dst, int R, int C)
{
  __shared__ float tile[64][65];
  const float* s = src + (size_t)blockIdx.z * R * C;
  u16* d = dst + (size_t)blockIdx.z * R * C;
  const int tx = threadIdx.x & 63, ty = threadIdx.x >> 6;   // ty 0..3
  const int c = blockIdx.x * 64 + tx;
#pragma unroll
  for (int i = 0; i < 16; ++i) {
    const int r = blockIdx.y * 64 + ty + i * 4;
    tile[ty + i * 4][tx] = s[(size_t)r * C + c];
  }
  __syncthreads();
  const int h = threadIdx.x & 7;        // row-octet within the 64-row tile
  const int cl = threadIdx.x >> 3;      // 0..31
  const int rr = blockIdx.y * 64 + h * 8;
#pragma unroll
  for (int i = 0; i < 2; ++i) {
    const int ccl = cl + i * 32;
    const int cc = blockIdx.x * 64 + ccl;
    short8 pack;
#pragma unroll
    for (int j = 0; j < 8; ++j)
      pack[j] = (short)f2bf(tile[h * 8 + j][ccl]);
    *(short8*)&d[(size_t)cc * R + rr] = pack;
  }
}

// ---------------- sparse MoE FFN: R12-style 2-phase pipelined gather-GEMM ----------------
template <int SLOT1>
__global__ __launch_bounds__(256) void k_ffn_slot(
    const u16* __restrict__ tbf, const u16* __restrict__ BT,
    const float* __restrict__ eb, const int* __restrict__ counts,
    const int* __restrict__ tlist, const float* __restrict__ wlist,
    u16* __restrict__ moe)
{
  const int e = blockIdx.z;
  const int cnt = counts[SLOT1 * NEXP + e];
  const int mb = blockIdx.y;
  if (mb * 128 >= cnt) return;
  const int base = (SLOT1 * NEXP + e) * T_TOKENS + mb * 128;
  const int lim = cnt - mb * 128;

  __shared__ u16 aT[2][128 * 64];
  __shared__ u16 bT[2][128 * 64];
  const int tid = threadIdx.x;
  const int wave = tid >> 6, lane = tid & 63;
  const int wm = wave >> 1, wn = wave & 1;
  const int kg = lane >> 4, fr = lane & 15;
  const int n0 = blockIdx.x * 128;
  const u16* Be = BT + (size_t)e * DFF * DMODEL;
  const int K = DMODEL, NT = K / 64;              // 12 K-tiles

  int gs8[2], lOf[2]; size_t gBo[2]; int tokA[2][2];
#pragma unroll
  for (int i = 0; i < 2; ++i) {
    const int cch = i * 256 + tid, rl = cch >> 3, sft = cch & 7;
    const int rb = (rl & 31) + ((rl >> 5) << 6);
    gs8[i] = (sft ^ (rl & 7)) * 8;
    lOf[i] = rb * 64 + sft * 8;
    gBo[i] = (size_t)(n0 + rb) * K + gs8[i];
#pragma unroll
    for (int hh = 0; hh < 2; ++hh) {
      const int row = rb + hh * 32;
      tokA[i][hh] = tlist[base + (row < lim ? row : lim - 1)];
    }
  }
  auto stageA = [&](int kb, u16* buf, int h) {
#pragma unroll
    for (int i = 0; i < 2; ++i)
      async_load16(tbf + (size_t)tokA[i][h] * K + kb + gs8[i], buf + lOf[i] + h * 2048);
  };
  auto stageB = [&](int kb, u16* buf, int h) {
#pragma unroll
    for (int i = 0; i < 2; ++i)
      async_load16(Be + gBo[i] + (size_t)(h * 32) * K + kb, buf + lOf[i] + h * 2048);
  };

  f32x4 acc[4][4] = {};
  short8 afA[2][2], afB[2][2], bf[4][2];

  stageA(0, aT[0], 0); stageA(0, aT[0], 1);
  stageB(0, bT[0], 0); stageB(0, bT[0], 1);
  stageA(64, aT[1], 0); stageB(64, bT[1], 0); stageB(64, bT[1], 1);
  VMCNT(6); SCHEDB(); SBAR();
#pragma unroll
  for (int i = 0; i < 2; ++i)
#pragma unroll
    for (int kk = 0; kk < 2; ++kk)
      afA[i][kk] = frag(aT[0], wm * 64 + i * 16 + fr, kk * 4 + kg);
#pragma unroll
  for (int j = 0; j < 4; ++j)
#pragma unroll
    for (int kk = 0; kk < 2; ++kk)
      bf[j][kk] = frag(bT[0], wn * 64 + j * 16 + fr, kk * 4 + kg);

  for (int t = 0; t < NT; ++t) {
    const int cur = t & 1;
    const u16* a_ = aT[cur];
    u16* aw = aT[cur]; u16* bw = bT[cur];
    u16* an = aT[cur ^ 1]; const u16* bn = bT[cur ^ 1];
    const int kb1 = (t + 1) * 64, kb2 = (t + 2) * 64;

    // ---- Phase A ----
    if (t + 1 < NT) stageA(kb1, an, 1);
    __builtin_amdgcn_s_setprio(1);
#pragma unroll
    for (int i = 0; i < 2; ++i)
#pragma unroll
      for (int j = 0; j < 4; ++j)
#pragma unroll
        for (int kk = 0; kk < 2; ++kk)
          acc[i][j] = __builtin_amdgcn_mfma_f32_16x16x32_bf16(afA[i][kk], bf[j][kk], acc[i][j], 0, 0, 0);
    __builtin_amdgcn_s_setprio(0);
#pragma unroll
    for (int i = 0; i < 2; ++i)
#pragma unroll
      for (int kk = 0; kk < 2; ++kk)
        afB[i][kk] = frag(a_, wm * 64 + 32 + i * 16 + fr, kk * 4 + kg);
    if (t + 1 < NT) { VMCNT(2); SCHEDB(); }
    SBAR();

    // ---- Phase B ----
    if (t + 2 < NT) { stageA(kb2, aw, 0); stageB(kb2, bw, 0); stageB(kb2, bw, 1); }
    __builtin_amdgcn_s_setprio(1);
#pragma unroll
    for (int i = 0; i < 2; ++i)
#pragma unroll
      for (int j = 0; j < 4; ++j)
#pragma unroll
        for (int kk = 0; kk < 2; ++kk)
          acc[i + 2][j] = __builtin_amdgcn_mfma_f32_16x16x32_bf16(afB[i][kk], bf[j][kk], acc[i + 2][j], 0, 0, 0);
    __builtin_amdgcn_s_setprio(0);
    if (t + 1 < NT) {
#pragma unroll
      for (int i = 0; i < 2; ++i)
#pragma unroll
        for (int kk = 0; kk < 2; ++kk)
          afA[i][kk] = frag(an, wm * 64 + i * 16 + fr, kk * 4 + kg);
#pragma unroll
      for (int j = 0; j < 4; ++j)
#pragma unroll
        for (int kk = 0; kk < 2; ++kk)
          bf[j][kk] = frag(bn, wn * 64 + j * 16 + fr, kk * 4 + kg);
      if (t + 2 < NT) { VMCNT(6); } else { VMCNT(0); }
      SCHEDB();
    }
    SBAR();
  }

  int trow[4][4]; float wrow[4][4];
#pragma unroll
  for (int i = 0; i < 4; ++i)
#pragma unroll
    for (int r = 0; r < 4; ++r) {
      const int row = wm * 64 + i * 16 + kg * 4 + r;
      if (row < lim) { trow[i][r] = tlist[base + row]; wrow[i][r] = wlist[base + row]; }
      else trow[i][r] = -1;
    }
#pragma unroll
  for (int j = 0; j < 4; ++j) {
    const int col = n0 + wn * 64 + j * 16 + fr;
    const float b = eb[e * DFF + col];
#pragma unroll
    for (int i = 0; i < 4; ++i)
#pragma unroll
      for (int r = 0; r < 4; ++r) {
        if (trow[i][r] < 0) continue;
        float v = acc[i][j][r] + b;
        v = v > 0.f ? v : 0.f;
        v *= wrow[i][r];
        u16* dst = &moe[(size_t)trow[i][r] * DFF + col];
        if (SLOT1) v += bf2f(*dst);
        *dst = f2bf(v);
      }
  }
}

// ---------------- head GEMM: 256^2 tile, 2-phase (R12/R13, best verified) ----------------
__global__ __launch_bounds__(512, 2) void k_head(
    const u16* __restrict__ A, const u16* __restrict__ BT,
    const float* __restrict__ bias, float* __restrict__ C)
{
  __shared__ u16 aL[2][256 * 64];
  __shared__ u16 bL[2][256 * 64];
  const int tid = threadIdx.x;
  const int lane = tid & 63, wave = tid >> 6;
  const int wm = wave >> 2, wn = wave & 3;         // 2 x 4 wave grid
  const int kg = lane >> 4, fr = lane & 15;
  const int wg = (int)blockIdx.x;
  const int swz = (wg & 7) * 250 + (wg >> 3);      // bijective XCD swizzle (2000=8*250)
  const int m0 = (swz & 15) * 256;
  const int n0 = (swz >> 4) * 256;
  const int K = DFF, NT = K / 64;                  // 48 tiles

  size_t gAo[2], gBo[2]; int lAo[2], lBo[2];
#pragma unroll
  for (int i = 0; i < 2; ++i) {
    const int c = i * 512 + tid, rl = c >> 3, s = c & 7;
    const int rA = (rl & 63) + ((rl >> 6) << 7);
    const int gsA = s ^ (rA & 7);
    gAo[i] = (size_t)(m0 + rA) * K + gsA * 8;
    lAo[i] = rA * 64 + s * 8;
    const int rB = (rl & 31) + ((rl >> 5) << 6);
    const int gsB = s ^ (rB & 7);
    gBo[i] = (size_t)(n0 + rB) * K + gsB * 8;
    lBo[i] = rB * 64 + s * 8;
  }
  auto stageA = [&](int kb, u16* buf, int h) {
#pragma unroll
    for (int i = 0; i < 2; ++i)
      async_load16(A + gAo[i] + (size_t)(h * 64) * K + kb, buf + lAo[i] + h * 4096);
  };
  auto stageB = [&](int kb, u16* buf, int h) {
#pragma unroll
    for (int i = 0; i < 2; ++i)
      async_load16(BT + gBo[i] + (size_t)(h * 32) * K + kb, buf + lBo[i] + h * 2048);
  };

  f32x4 acc[8][4] = {};
  short8 af[4][2], bfl[2][2], bfh[2][2];

  stageA(0, aL[0], 0); stageA(0, aL[0], 1);
  stageB(0, bL[0], 0); stageB(0, bL[0], 1);
  stageA(64, aL[1], 0); stageB(64, bL[1], 0); stageB(64, bL[1], 1);
  VMCNT(6);
  SCHEDB();
  SBAR();
#pragma unroll
  for (int mi = 0; mi < 4; ++mi)
#pragma unroll
    for (int kk = 0; kk < 2; ++kk)
      af[mi][kk] = frag(aL[0], wm * 128 + mi * 16 + fr, kk * 4 + kg);
#pragma unroll
  for (int ni = 0; ni < 2; ++ni)
#pragma unroll
    for (int kk = 0; kk < 2; ++kk) {
      bfl[ni][kk] = frag(bL[0], wn * 64 + ni * 16 + fr, kk * 4 + kg);
      bfh[ni][kk] = frag(bL[0], wn * 64 + 32 + ni * 16 + fr, kk * 4 + kg);
    }

  for (int t = 0; t < NT; ++t) {
    const int cur = t & 1;
    const u16* a_ = aL[cur];
    u16* aw = aL[cur];
    u16* bw = bL[cur];
    u16* an = aL[cur ^ 1];
    const u16* bn = bL[cur ^ 1];
    const int kb1 = (t + 1) * 64, kb2 = (t + 2) * 64;

    // ======== Phase A ========
    if (t + 1 < NT) stageA(kb1, an, 1);
    __builtin_amdgcn_s_setprio(1);
#pragma unroll
    for (int mi = 0; mi < 4; ++mi)
#pragma unroll
      for (int ni = 0; ni < 2; ++ni)
#pragma unroll
        for (int kk = 0; kk < 2; ++kk) {
          acc[mi][ni]     = __builtin_amdgcn_mfma_f32_16x16x32_bf16(af[mi][kk], bfl[ni][kk], acc[mi][ni], 0, 0, 0);
          acc[mi][ni + 2] = __builtin_amdgcn_mfma_f32_16x16x32_bf16(af[mi][kk], bfh[ni][kk], acc[mi][ni + 2], 0, 0, 0);
        }
    __builtin_amdgcn_s_setprio(0);
#pragma unroll
    for (int mi = 0; mi < 4; ++mi)
#pragma unroll
      for (int kk = 0; kk < 2; ++kk)
        af[mi][kk] = frag(a_, wm * 128 + 64 + mi * 16 + fr, kk * 4 + kg);
    if (t + 1 < NT) { VMCNT(2); SCHEDB(); }
    SBAR();

    // ======== Phase B ========
    if (t + 2 < NT) { stageA(kb2, aw, 0); stageB(kb2, bw, 0); stageB(kb2, bw, 1); }
    __builtin_amdgcn_s_setprio(1);
#pragma unroll
    for (int mi = 0; mi < 4; ++mi)
#pragma unroll
      for (int ni = 0; ni < 2; ++ni)
#pragma unroll
        for (int kk = 0; kk < 2; ++kk) {
          acc[mi + 4][ni]     = __builtin_amdgcn_mfma_f32_16x16x32_bf16(af[mi][kk], bfl[ni][kk], acc[mi + 4][ni], 0, 0, 0);
          acc[mi + 4][ni + 2] = __builtin_amdgcn_mfma_f32_16x16x32_bf16(af[mi][kk], bfh[ni][kk], acc[mi + 4][ni + 2], 0, 0, 0);
        }
    __builtin_amdgcn_s_setprio(0);
    if (t + 1 < NT) {
#pragma unroll
      for (int mi = 0; mi < 4; ++mi)
#pragma unroll
        for (int kk = 0; kk < 2; ++kk)
          af[mi][kk] = frag(an, wm * 128 + mi * 16 + fr, kk * 4 + kg);
#pragma unroll
      for (int ni = 0; ni < 2; ++ni)
#pragma unroll
        for (int kk = 0; kk < 2; ++kk) {
          bfl[ni][kk] = frag(bn, wn * 64 + ni * 16 + fr, kk * 4 + kg);
          bfh[ni][kk] = frag(bn, wn * 64 + 32 + ni * 16 + fr, kk * 4 + kg);
        }
      if (t + 2 < NT) { VMCNT(6); } else { VMCNT(0); }
      SCHEDB();
    }
    SBAR();
  }

  // epilogue: non-temporal stores
#pragma unroll
  for (int ni = 0; ni < 4; ++ni) {
    const int col = n0 + wn * 64 + ni * 16 + fr;
    const float b = bias[col];
#pragma unroll
    for (int mi = 0; mi < 8; ++mi) {
      const int row = m0 + wm * 128 + (mi >> 2) * 64 + (mi & 3) * 16 + kg * 4;
#pragma unroll
      for (int r = 0; r < 4; ++r)
        __builtin_nontemporal_store(acc[mi][ni][r] + b,
                                    &C[(size_t)(row + r) * NVOCAB + col]);
    }
  }
}

extern "C" void kernel_launch(void* const* d_in, const int* in_sizes, int n_in,
                              void* d_out, int out_size, void* d_ws, size_t ws_size,
                              hipStream_t stream) {
  const int*   x     = (const int*)d_in[0];
  const float* emb   = (const float*)d_in[1];
  const float* gw    = (const float*)d_in[2];
  const float* gb    = (const float*)d_in[3];
  const float* expw  = (const float*)d_in[4];
  const float* expb  = (const float*)d_in[5];
  const float* headw = (const float*)d_in[6];
  const float* headb = (const float*)d_in[7];
  float* out = (float*)d_out;

  char* ws = (char*)d_ws;
  size_t off = 0;
  auto alloc = [&](size_t bytes) { size_t r = off; off += (bytes + 255) & ~(size_t)255; return r; };
  u16*   tbf    = (u16*)(ws + alloc((size_t)T_TOKENS * DMODEL * 2));
  int*   counts = (int*)(ws + alloc(2 * NEXP * 4));
  int*   tlist  = (int*)(ws + alloc((size_t)2 * NEXP * T_TOKENS * 4));
  float* wlist  = (float*)(ws + alloc((size_t)2 * NEXP * T_TOKENS * 4));
  u16*   expwT  = (u16*)(ws + alloc((size_t)NEXP * DFF * DMODEL * 2));
  u16*   headwT = (u16*)(ws + alloc((size_t)NVOCAB * DFF * 2));
  u16*   moe    = (u16*)(ws + alloc((size_t)T_TOKENS * DFF * 2));

  hipMemsetAsync(counts, 0, 2 * NEXP * 4, stream);
  k_embed_router<<<T_TOKENS, 256, 0, stream>>>(x, emb, gw, gb, tbf, counts, tlist, wlist);
  k_transpose_cvt<<<dim3(DFF / 64, DMODEL / 64, NEXP), 256, 0, stream>>>(expw, expwT, DMODEL, DFF);
  k_transpose_cvt<<<dim3(NVOCAB / 64, DFF / 64, 1), 256, 0, stream>>>(headw, headwT, DFF, NVOCAB);
  k_ffn_slot<0><<<dim3(DFF / 128, T_TOKENS / 128, NEXP), 256, 0, stream>>>(
      tbf, expwT, expb, counts, tlist, wlist, moe);
  k_ffn_slot<1><<<dim3(DFF / 128, T_TOKENS / 128, NEXP), 256, 0, stream>>>(
      tbf, expwT, expb, counts, tlist, wlist, moe);
  k_head<<<(T_TOKENS / 256) * (NVOCAB / 256), 512, 0, stream>>>(moe, headwT, headb, out);
}

// Round 17
// 1165.804 us; speedup vs baseline: 1.0019x; 1.0019x over previous
//
#include <hip/hip_runtime.h>

typedef unsigned short u16;
typedef __attribute__((ext_vector_type(8))) short short8;
typedef __attribute__((ext_vector_type(4))) float f32x4;

#define T_TOKENS 4096
#define DMODEL   768
#define DFF      3072
#define NEXP     8
#define NVOCAB   32000

// fused-front grid layout
#define EMB_BLOCKS   T_TOKENS                      // 4096
#define TEXP_BX      (DFF / 64)                    // 48
#define TEXP_BY      (DMODEL / 64)                 // 12
#define TEXP_BLOCKS  (TEXP_BX * TEXP_BY * NEXP)    // 4608
#define THEAD_BX     (NVOCAB / 64)                 // 500
#define THEAD_BY     (DFF / 64)                    // 48
#define THEAD_BLOCKS (THEAD_BX * THEAD_BY)         // 24000
#define FRONT_BLOCKS (EMB_BLOCKS + TEXP_BLOCKS + THEAD_BLOCKS)

__device__ __forceinline__ u16 f2bf(float f) {
  unsigned u = __float_as_uint(f);
  u += 0x7FFFu + ((u >> 16) & 1u);
  return (u16)(u >> 16);
}
__device__ __forceinline__ float bf2f(u16 b) {
  return __uint_as_float(((unsigned)b) << 16);
}

__device__ __forceinline__ void async_load16(const void* g, void* lds) {
  __builtin_amdgcn_global_load_lds((const __attribute__((address_space(1))) void*)g,
                                   (__attribute__((address_space(3))) void*)lds, 16, 0, 0);
}

#define SBAR() __builtin_amdgcn_s_barrier()
#define VMCNT(n) asm volatile("s_waitcnt vmcnt(" #n ")")
#define SCHEDB() __builtin_amdgcn_sched_barrier(0)

__device__ __forceinline__ short8 frag(const u16* buf, int row, int kc) {
  return *(const short8*)(buf + (row * 8 + (kc ^ (row & 7))) * 8);
}

// ---------------- fused front: embed+router | transpose(expw) | transpose(headw) ----------------
// All three phases are mutually independent (disjoint reads/writes); fusing
// them makes their blocks co-schedulable (overlapping memory streams) and
// removes two launch/drain boundaries. Bodies are identical to the previous
// separate kernels; only the flat blockIdx.x decode is new.
__global__ __launch_bounds__(256) void k_front(
    const int* __restrict__ x, const float* __restrict__ emb,
    const float* __restrict__ gw, const float* __restrict__ gb,
    u16* __restrict__ tbf, int* __restrict__ counts,
    int* __restrict__ tlist, float* __restrict__ wlist,
    const float* __restrict__ expw, u16* __restrict__ expwT,
    const float* __restrict__ headw, u16* __restrict__ headwT)
{
  __shared__ float tile[64][65];                  // transpose staging (16.6 KB)
  __shared__ float partial[4][NEXP];              // router partials
  int b = (int)blockIdx.x;

  if (b < EMB_BLOCKS) {
    // ---- embed + router + top2 list build (body = old k_embed_router) ----
    const int t = b;
    const int tok = x[t];
    const float* er = emb + (size_t)tok * DMODEL;
    float p[NEXP];
#pragma unroll
    for (int e = 0; e < NEXP; ++e) p[e] = 0.f;
#pragma unroll
    for (int i = 0; i < 3; ++i) {
      const int d = threadIdx.x + i * 256;
      const float v = er[d];
      tbf[(size_t)t * DMODEL + d] = f2bf(v);
#pragma unroll
      for (int e = 0; e < NEXP; ++e) p[e] += v * gw[d * NEXP + e];
    }
#pragma unroll
    for (int e = 0; e < NEXP; ++e)
#pragma unroll
      for (int m = 32; m >= 1; m >>= 1) p[e] += __shfl_xor(p[e], m);
    const int lane = threadIdx.x & 63, wv = threadIdx.x >> 6;
    if (lane == 0)
      for (int e = 0; e < NEXP; ++e) partial[wv][e] = p[e];
    __syncthreads();
    if (threadIdx.x == 0) {
      float l[NEXP];
      for (int e = 0; e < NEXP; ++e)
        l[e] = partial[0][e] + partial[1][e] + partial[2][e] + partial[3][e] + gb[e];
      int i0 = 0;
      for (int e = 1; e < NEXP; ++e) if (l[e] > l[i0]) i0 = e;   // ties: first (jax)
      int i1 = -1;
      for (int e = 0; e < NEXP; ++e) { if (e == i0) continue; if (i1 < 0 || l[e] > l[i1]) i1 = e; }
      const float w0 = 1.f / (1.f + expf(l[i1] - l[i0]));
      int p0 = atomicAdd(&counts[0 * NEXP + i0], 1);
      tlist[(0 * NEXP + i0) * T_TOKENS + p0] = t;
      wlist[(0 * NEXP + i0) * T_TOKENS + p0] = w0;
      int p1 = atomicAdd(&counts[1 * NEXP + i1], 1);
      tlist[(1 * NEXP + i1) * T_TOKENS + p1] = t;
      wlist[(1 * NEXP + i1) * T_TOKENS + p1] = 1.f - w0;
    }
    return;
  }
  b -= EMB_BLOCKS;

  // ---- transpose + fp32->bf16 (body = old k_transpose_cvt, 16B stores) ----
  const float* src; u16* dst; int R, C, bx, by;
  if (b < TEXP_BLOCKS) {
    const int z = b / (TEXP_BX * TEXP_BY);
    const int rem = b - z * (TEXP_BX * TEXP_BY);
    by = rem / TEXP_BX;
    bx = rem - by * TEXP_BX;
    R = DMODEL; C = DFF;
    src = expw + (size_t)z * R * C;
    dst = expwT + (size_t)z * R * C;
  } else {
    b -= TEXP_BLOCKS;
    by = b / THEAD_BX;
    bx = b - by * THEAD_BX;
    R = DFF; C = NVOCAB;
    src = headw;
    dst = headwT;
  }
  {
    const int tx = threadIdx.x & 63, ty = threadIdx.x >> 6;   // ty 0..3
    const int c = bx * 64 + tx;
#pragma unroll
    for (int i = 0; i < 16; ++i) {
      const int r = by * 64 + ty + i * 4;
      tile[ty + i * 4][tx] = src[(size_t)r * C + c];
    }
    __syncthreads();
    const int h = threadIdx.x & 7;        // row-octet within the 64-row tile
    const int cl = threadIdx.x >> 3;      // 0..31
    const int rr = by * 64 + h * 8;
#pragma unroll
    for (int i = 0; i < 2; ++i) {
      const int ccl = cl + i * 32;
      const int cc = bx * 64 + ccl;
      short8 pack;
#pragma unroll
      for (int j = 0; j < 8; ++j)
        pack[j] = (short)f2bf(tile[h * 8 + j][ccl]);
      *(short8*)&dst[(size_t)cc * R + rr] = pack;
    }
  }
}

// ---------------- sparse MoE FFN: R12-style 2-phase pipelined gather-GEMM ----------------
template <int SLOT1>
__global__ __launch_bounds__(256) void k_ffn_slot(
    const u16* __restrict__ tbf, const u16* __restrict__ BT,
    const float* __restrict__ eb, const int* __restrict__ counts,
    const int* __restrict__ tlist, const float* __restrict__ wlist,
    u16* __restrict__ moe)
{
  const int e = blockIdx.z;
  const int cnt = counts[SLOT1 * NEXP + e];
  const int mb = blockIdx.y;
  if (mb * 128 >= cnt) return;
  const int base = (SLOT1 * NEXP + e) * T_TOKENS + mb * 128;
  const int lim = cnt - mb * 128;

  __shared__ u16 aT[2][128 * 64];
  __shared__ u16 bT[2][128 * 64];
  const int tid = threadIdx.x;
  const int wave = tid >> 6, lane = tid & 63;
  const int wm = wave >> 1, wn = wave & 1;
  const int kg = lane >> 4, fr = lane & 15;
  const int n0 = blockIdx.x * 128;
  const u16* Be = BT + (size_t)e * DFF * DMODEL;
  const int K = DMODEL, NT = K / 64;              // 12 K-tiles

  int gs8[2], lOf[2]; size_t gBo[2]; int tokA[2][2];
#pragma unroll
  for (int i = 0; i < 2; ++i) {
    const int cch = i * 256 + tid, rl = cch >> 3, sft = cch & 7;
    const int rb = (rl & 31) + ((rl >> 5) << 6);
    gs8[i] = (sft ^ (rl & 7)) * 8;
    lOf[i] = rb * 64 + sft * 8;
    gBo[i] = (size_t)(n0 + rb) * K + gs8[i];
#pragma unroll
    for (int hh = 0; hh < 2; ++hh) {
      const int row = rb + hh * 32;
      tokA[i][hh] = tlist[base + (row < lim ? row : lim - 1)];
    }
  }
  auto stageA = [&](int kb, u16* buf, int h) {
#pragma unroll
    for (int i = 0; i < 2; ++i)
      async_load16(tbf + (size_t)tokA[i][h] * K + kb + gs8[i], buf + lOf[i] + h * 2048);
  };
  auto stageB = [&](int kb, u16* buf, int h) {
#pragma unroll
    for (int i = 0; i < 2; ++i)
      async_load16(Be + gBo[i] + (size_t)(h * 32) * K + kb, buf + lOf[i] + h * 2048);
  };

  f32x4 acc[4][4] = {};
  short8 afA[2][2], afB[2][2], bf[4][2];

  stageA(0, aT[0], 0); stageA(0, aT[0], 1);
  stageB(0, bT[0], 0); stageB(0, bT[0], 1);
  stageA(64, aT[1], 0); stageB(64, bT[1], 0); stageB(64, bT[1], 1);
  VMCNT(6); SCHEDB(); SBAR();
#pragma unroll
  for (int i = 0; i < 2; ++i)
#pragma unroll
    for (int kk = 0; kk < 2; ++kk)
      afA[i][kk] = frag(aT[0], wm * 64 + i * 16 + fr, kk * 4 + kg);
#pragma unroll
  for (int j = 0; j < 4; ++j)
#pragma unroll
    for (int kk = 0; kk < 2; ++kk)
      bf[j][kk] = frag(bT[0], wn * 64 + j * 16 + fr, kk * 4 + kg);

  for (int t = 0; t < NT; ++t) {
    const int cur = t & 1;
    const u16* a_ = aT[cur];
    u16* aw = aT[cur]; u16* bw = bT[cur];
    u16* an = aT[cur ^ 1]; const u16* bn = bT[cur ^ 1];
    const int kb1 = (t + 1) * 64, kb2 = (t + 2) * 64;

    // ---- Phase A ----
    if (t + 1 < NT) stageA(kb1, an, 1);
    __builtin_amdgcn_s_setprio(1);
#pragma unroll
    for (int i = 0; i < 2; ++i)
#pragma unroll
      for (int j = 0; j < 4; ++j)
#pragma unroll
        for (int kk = 0; kk < 2; ++kk)
          acc[i][j] = __builtin_amdgcn_mfma_f32_16x16x32_bf16(afA[i][kk], bf[j][kk], acc[i][j], 0, 0, 0);
    __builtin_amdgcn_s_setprio(0);
#pragma unroll
    for (int i = 0; i < 2; ++i)
#pragma unroll
      for (int kk = 0; kk < 2; ++kk)
        afB[i][kk] = frag(a_, wm * 64 + 32 + i * 16 + fr, kk * 4 + kg);
    if (t + 1 < NT) { VMCNT(2); SCHEDB(); }
    SBAR();

    // ---- Phase B ----
    if (t + 2 < NT) { stageA(kb2, aw, 0); stageB(kb2, bw, 0); stageB(kb2, bw, 1); }
    __builtin_amdgcn_s_setprio(1);
#pragma unroll
    for (int i = 0; i < 2; ++i)
#pragma unroll
      for (int j = 0; j < 4; ++j)
#pragma unroll
        for (int kk = 0; kk < 2; ++kk)
          acc[i + 2][j] = __builtin_amdgcn_mfma_f32_16x16x32_bf16(afB[i][kk], bf[j][kk], acc[i + 2][j], 0, 0, 0);
    __builtin_amdgcn_s_setprio(0);
    if (t + 1 < NT) {
#pragma unroll
      for (int i = 0; i < 2; ++i)
#pragma unroll
        for (int kk = 0; kk < 2; ++kk)
          afA[i][kk] = frag(an, wm * 64 + i * 16 + fr, kk * 4 + kg);
#pragma unroll
      for (int j = 0; j < 4; ++j)
#pragma unroll
        for (int kk = 0; kk < 2; ++kk)
          bf[j][kk] = frag(bn, wn * 64 + j * 16 + fr, kk * 4 + kg);
      if (t + 2 < NT) { VMCNT(6); } else { VMCNT(0); }
      SCHEDB();
    }
    SBAR();
  }

  int trow[4][4]; float wrow[4][4];
#pragma unroll
  for (int i = 0; i < 4; ++i)
#pragma unroll
    for (int r = 0; r < 4; ++r) {
      const int row = wm * 64 + i * 16 + kg * 4 + r;
      if (row < lim) { trow[i][r] = tlist[base + row]; wrow[i][r] = wlist[base + row]; }
      else trow[i][r] = -1;
    }
#pragma unroll
  for (int j = 0; j < 4; ++j) {
    const int col = n0 + wn * 64 + j * 16 + fr;
    const float b = eb[e * DFF + col];
#pragma unroll
    for (int i = 0; i < 4; ++i)
#pragma unroll
      for (int r = 0; r < 4; ++r) {
        if (trow[i][r] < 0) continue;
        float v = acc[i][j][r] + b;
        v = v > 0.f ? v : 0.f;
        v *= wrow[i][r];
        u16* dst = &moe[(size_t)trow[i][r] * DFF + col];
        if (SLOT1) v += bf2f(*dst);
        *dst = f2bf(v);
      }
  }
}

// ---------------- head GEMM: 256^2 tile, 2-phase (R12/R13, best verified) ----------------
__global__ __launch_bounds__(512, 2) void k_head(
    const u16* __restrict__ A, const u16* __restrict__ BT,
    const float* __restrict__ bias, float* __restrict__ C)
{
  __shared__ u16 aL[2][256 * 64];
  __shared__ u16 bL[2][256 * 64];
  const int tid = threadIdx.x;
  const int lane = tid & 63, wave = tid >> 6;
  const int wm = wave >> 2, wn = wave & 3;         // 2 x 4 wave grid
  const int kg = lane >> 4, fr = lane & 15;
  const int wg = (int)blockIdx.x;
  const int swz = (wg & 7) * 250 + (wg >> 3);      // bijective XCD swizzle (2000=8*250)
  const int m0 = (swz & 15) * 256;
  const int n0 = (swz >> 4) * 256;
  const int K = DFF, NT = K / 64;                  // 48 tiles

  size_t gAo[2], gBo[2]; int lAo[2], lBo[2];
#pragma unroll
  for (int i = 0; i < 2; ++i) {
    const int c = i * 512 + tid, rl = c >> 3, s = c & 7;
    const int rA = (rl & 63) + ((rl >> 6) << 7);
    const int gsA = s ^ (rA & 7);
    gAo[i] = (size_t)(m0 + rA) * K + gsA * 8;
    lAo[i] = rA * 64 + s * 8;
    const int rB = (rl & 31) + ((rl >> 5) << 6);
    const int gsB = s ^ (rB & 7);
    gBo[i] = (size_t)(n0 + rB) * K + gsB * 8;
    lBo[i] = rB * 64 + s * 8;
  }
  auto stageA = [&](int kb, u16* buf, int h) {
#pragma unroll
    for (int i = 0; i < 2; ++i)
      async_load16(A + gAo[i] + (size_t)(h * 64) * K + kb, buf + lAo[i] + h * 4096);
  };
  auto stageB = [&](int kb, u16* buf, int h) {
#pragma unroll
    for (int i = 0; i < 2; ++i)
      async_load16(BT + gBo[i] + (size_t)(h * 32) * K + kb, buf + lBo[i] + h * 2048);
  };

  f32x4 acc[8][4] = {};
  short8 af[4][2], bfl[2][2], bfh[2][2];

  stageA(0, aL[0], 0); stageA(0, aL[0], 1);
  stageB(0, bL[0], 0); stageB(0, bL[0], 1);
  stageA(64, aL[1], 0); stageB(64, bL[1], 0); stageB(64, bL[1], 1);
  VMCNT(6);
  SCHEDB();
  SBAR();
#pragma unroll
  for (int mi = 0; mi < 4; ++mi)
#pragma unroll
    for (int kk = 0; kk < 2; ++kk)
      af[mi][kk] = frag(aL[0], wm * 128 + mi * 16 + fr, kk * 4 + kg);
#pragma unroll
  for (int ni = 0; ni < 2; ++ni)
#pragma unroll
    for (int kk = 0; kk < 2; ++kk) {
      bfl[ni][kk] = frag(bL[0], wn * 64 + ni * 16 + fr, kk * 4 + kg);
      bfh[ni][kk] = frag(bL[0], wn * 64 + 32 + ni * 16 + fr, kk * 4 + kg);
    }

  for (int t = 0; t < NT; ++t) {
    const int cur = t & 1;
    const u16* a_ = aL[cur];
    u16* aw = aL[cur];
    u16* bw = bL[cur];
    u16* an = aL[cur ^ 1];
    const u16* bn = bL[cur ^ 1];
    const int kb1 = (t + 1) * 64, kb2 = (t + 2) * 64;

    // ======== Phase A ========
    if (t + 1 < NT) stageA(kb1, an, 1);
    __builtin_amdgcn_s_setprio(1);
#pragma unroll
    for (int mi = 0; mi < 4; ++mi)
#pragma unroll
      for (int ni = 0; ni < 2; ++ni)
#pragma unroll
        for (int kk = 0; kk < 2; ++kk) {
          acc[mi][ni]     = __builtin_amdgcn_mfma_f32_16x16x32_bf16(af[mi][kk], bfl[ni][kk], acc[mi][ni], 0, 0, 0);
          acc[mi][ni + 2] = __builtin_amdgcn_mfma_f32_16x16x32_bf16(af[mi][kk], bfh[ni][kk], acc[mi][ni + 2], 0, 0, 0);
        }
    __builtin_amdgcn_s_setprio(0);
#pragma unroll
    for (int mi = 0; mi < 4; ++mi)
#pragma unroll
      for (int kk = 0; kk < 2; ++kk)
        af[mi][kk] = frag(a_, wm * 128 + 64 + mi * 16 + fr, kk * 4 + kg);
    if (t + 1 < NT) { VMCNT(2); SCHEDB(); }
    SBAR();

    // ======== Phase B ========
    if (t + 2 < NT) { stageA(kb2, aw, 0); stageB(kb2, bw, 0); stageB(kb2, bw, 1); }
    __builtin_amdgcn_s_setprio(1);
#pragma unroll
    for (int mi = 0; mi < 4; ++mi)
#pragma unroll
      for (int ni = 0; ni < 2; ++ni)
#pragma unroll
        for (int kk = 0; kk < 2; ++kk) {
          acc[mi + 4][ni]     = __builtin_amdgcn_mfma_f32_16x16x32_bf16(af[mi][kk], bfl[ni][kk], acc[mi + 4][ni], 0, 0, 0);
          acc[mi + 4][ni + 2] = __builtin_amdgcn_mfma_f32_16x16x32_bf16(af[mi][kk], bfh[ni][kk], acc[mi + 4][ni + 2], 0, 0, 0);
        }
    __builtin_amdgcn_s_setprio(0);
    if (t + 1 < NT) {
#pragma unroll
      for (int mi = 0; mi < 4; ++mi)
#pragma unroll
        for (int kk = 0; kk < 2; ++kk)
          af[mi][kk] = frag(an, wm * 128 + mi * 16 + fr, kk * 4 + kg);
#pragma unroll
      for (int ni = 0; ni < 2; ++ni)
#pragma unroll
        for (int kk = 0; kk < 2; ++kk) {
          bfl[ni][kk] = frag(bn, wn * 64 + ni * 16 + fr, kk * 4 + kg);
          bfh[ni][kk] = frag(bn, wn * 64 + 32 + ni * 16 + fr, kk * 4 + kg);
        }
      if (t + 2 < NT) { VMCNT(6); } else { VMCNT(0); }
      SCHEDB();
    }
    SBAR();
  }

  // epilogue: non-temporal stores
#pragma unroll
  for (int ni = 0; ni < 4; ++ni) {
    const int col = n0 + wn * 64 + ni * 16 + fr;
    const float b = bias[col];
#pragma unroll
    for (int mi = 0; mi < 8; ++mi) {
      const int row = m0 + wm * 128 + (mi >> 2) * 64 + (mi & 3) * 16 + kg * 4;
#pragma unroll
      for (int r = 0; r < 4; ++r)
        __builtin_nontemporal_store(acc[mi][ni][r] + b,
                                    &C[(size_t)(row + r) * NVOCAB + col]);
    }
  }
}

extern "C" void kernel_launch(void* const* d_in, const int* in_sizes, int n_in,
                              void* d_out, int out_size, void* d_ws, size_t ws_size,
                              hipStream_t stream) {
  const int*   x     = (const int*)d_in[0];
  const float* emb   = (const float*)d_in[1];
  const float* gw    = (const float*)d_in[2];
  const float* gb    = (const float*)d_in[3];
  const float* expw  = (const float*)d_in[4];
  const float* expb  = (const float*)d_in[5];
  const float* headw = (const float*)d_in[6];
  const float* headb = (const float*)d_in[7];
  float* out = (float*)d_out;

  char* ws = (char*)d_ws;
  size_t off = 0;
  auto alloc = [&](size_t bytes) { size_t r = off; off += (bytes + 255) & ~(size_t)255; return r; };
  u16*   tbf    = (u16*)(ws + alloc((size_t)T_TOKENS * DMODEL * 2));
  int*   counts = (int*)(ws + alloc(2 * NEXP * 4));
  int*   tlist  = (int*)(ws + alloc((size_t)2 * NEXP * T_TOKENS * 4));
  float* wlist  = (float*)(ws + alloc((size_t)2 * NEXP * T_TOKENS * 4));
  u16*   expwT  = (u16*)(ws + alloc((size_t)NEXP * DFF * DMODEL * 2));
  u16*   headwT = (u16*)(ws + alloc((size_t)NVOCAB * DFF * 2));
  u16*   moe    = (u16*)(ws + alloc((size_t)T_TOKENS * DFF * 2));

  hipMemsetAsync(counts, 0, 2 * NEXP * 4, stream);
  k_front<<<FRONT_BLOCKS, 256, 0, stream>>>(x, emb, gw, gb, tbf, counts, tlist, wlist,
                                            expw, expwT, headw, headwT);
  k_ffn_slot<0><<<dim3(DFF / 128, T_TOKENS / 128, NEXP), 256, 0, stream>>>(
      tbf, expwT, expb, counts, tlist, wlist, moe);
  k_ffn_slot<1><<<dim3(DFF / 128, T_TOKENS / 128, NEXP), 256, 0, stream>>>(
      tbf, expwT, expb, counts, tlist, wlist, moe);
  k_head<<<(T_TOKENS / 256) * (NVOCAB / 256), 512, 0, stream>>>(moe, headwT, headb, out);
}